// Round 14
// baseline (194.022 us; speedup 1.0000x reference)
//
#include <hip/hip_runtime.h>
#include <hip/hip_bf16.h>

// GraphAttentionLayer: out = elu( softmax_row( where(adj>0, lrelu(src_i+dst_j), 0) ) @ wh )
//
// R13 post-mortem: full-line loader = slight regression (halved occupancy,
// added LDS hop); R12's cached 4-load cluster already covers lines jointly.
// REVERTED to R12 (best: 91.8us).
// R14 = SACRIFICIAL DIAGNOSTIC: R12 structure + k2 REPEAT=3 (opaque anti-CSE,
// scale 1/3). Warm passes (L3-resident) bypass DRAM -> warm-pass rate splits
// "HBM-delivery-bound" (warm <= 50us) from "internal-bound" (warm >= 60us),
// and k2's counters (VALUBusy/MfmaUtil/conflicts/FETCH) become visible past
// the ~150us ws-poison fills. Pre-committed decision tree in journal.
// NEXT ROUND: REPEAT=1 + the fix the tree selects.

constexpr int N_ROWS = 8192;
constexpr int F_IN   = 128;
constexpr int F_OUT  = 64;
constexpr int REPEAT = 3;          // DIAGNOSTIC (see header)
#define LRELU_A 0.2f
#define LOG2E   1.4426950408889634f

// workspace layout (bytes)
constexpr size_t OFF_WHT  = 0;                    // 1 MiB bf16 [f][row]
constexpr size_t OFF_SRC  = 1048576;              // 8192 f32 (x log2e)
constexpr size_t OFF_DST  = OFF_SRC + 32768;      // 8192 f32 (x log2e)
constexpr size_t OFF_LP   = OFF_DST + 32768;      // S*8192 f32
constexpr size_t OFF_ACC  = OFF_LP + 16 * 32768;  // 16*8192*64 f32 = 32 MiB

typedef __attribute__((ext_vector_type(4))) float f32x4;
typedef __attribute__((ext_vector_type(4))) int   i32x4;
typedef __attribute__((ext_vector_type(8))) short s16x8;

static __device__ __forceinline__ short f2bf(float f) {
  unsigned u = __float_as_uint(f);
  u = (u + 0x7fffu + ((u >> 16) & 1u)) >> 16;  // RNE
  return (short)u;
}

// ---------------- Kernel 1: wh = x@w ; src/dst (x log2e) ; whT (bf16) -------
__global__ __launch_bounds__(256) void k1_proj(
    const float* __restrict__ x, const float* __restrict__ w,
    const float* __restrict__ a, short* __restrict__ whT,
    float* __restrict__ src, float* __restrict__ dst)
{
  const int lane = threadIdx.x & 63;   // = output feature f
  const int wid  = threadIdx.x >> 6;
  const int rowBase = blockIdx.x * 32 + wid * 8;   // 8 rows per wave

  float acc[8];
#pragma unroll
  for (int r = 0; r < 8; ++r) acc[r] = 0.0f;

#pragma unroll 1
  for (int kc = 0; kc < 4; ++kc) {     // K chunks of 32 — ONE wreg live
    float wreg[32];
#pragma unroll
    for (int kk = 0; kk < 32; ++kk)
      wreg[kk] = w[(kc * 32 + kk) * F_OUT + lane];   // coalesced
#pragma unroll
    for (int r = 0; r < 8; ++r) {
      const f32x4* xp = (const f32x4*)(x + (size_t)(rowBase + r) * F_IN + kc * 32);
#pragma unroll
      for (int q = 0; q < 8; ++q) {    // wave-uniform broadcast loads
        f32x4 xv = xp[q];
        acc[r] = fmaf(xv.x, wreg[4*q+0], acc[r]);
        acc[r] = fmaf(xv.y, wreg[4*q+1], acc[r]);
        acc[r] = fmaf(xv.z, wreg[4*q+2], acc[r]);
        acc[r] = fmaf(xv.w, wreg[4*q+3], acc[r]);
      }
    }
  }

  s16x8 hb;
#pragma unroll
  for (int r = 0; r < 8; ++r) hb[r] = f2bf(acc[r]);
  *(s16x8*)&whT[(size_t)lane * N_ROWS + rowBase] = hb;

  const float aS = a[lane];
  const float aD = a[F_OUT + lane];
#pragma unroll
  for (int r = 0; r < 8; ++r) {
    float ts = acc[r] * aS;
    float td = acc[r] * aD;
#pragma unroll
    for (int off = 32; off > 0; off >>= 1) {
      ts += __shfl_xor(ts, off, 64);
      td += __shfl_xor(td, off, 64);
    }
    if (lane == 0) {
      src[rowBase + r] = ts * LOG2E;   // log2-domain scores
      dst[rowBase + r] = td * LOG2E;
    }
  }
}

// ---------------- Kernel 2: depth-3 pipelined fused mask+exp+PV (x3 diag) ---
// grid: (N/128, S) x 512 threads (8 waves x 16 rows). No in-loop barriers.
// Loop vmem = adj only (plain cached loads), 3 register buffers, unrolled NI=8.
template<int S>
__global__ __launch_bounds__(512, 2) void k2_attn(
    const int* __restrict__ adj, const short* __restrict__ whT,
    const float* __restrict__ src, const float* __restrict__ dst,
    float* __restrict__ acc_part, float* __restrict__ l_part)
{
  constexpr int JLEN = N_ROWS / S;   // 512
  constexpr int NI   = JLEN / 64;    // 8
  __shared__ short Blds[64 * JLEN];  // 64 KB, byte ^= (f&7)<<4 swizzle
  __shared__ float Dlds[JLEN];       // 2 KB

  const int tid  = threadIdx.x;
  const int lane = tid & 63;
  const int wid  = tid >> 6;
  const int s    = blockIdx.y;
  const int jbase = s * JLEN;
  const int rowg = blockIdx.x * 128 + wid * 16;
  const int r16  = lane & 15;
  const int kq   = lane >> 4;

  // ---- stage B slice (swizzled) + dst slice; ONE barrier total ----
#pragma unroll
  for (int q = 0; q < 8; ++q) {          // 4096 x 16B chunks / 512 threads
    const int m   = tid + q * 512;
    const int f   = m >> 6;
    const int c16 = m & 63;
    const s16x8 v = *(const s16x8*)(whT + (size_t)f * N_ROWS + jbase + c16 * 8);
    *(s16x8*)((char*)Blds + f * (JLEN * 2) + ((c16 * 16) ^ ((f & 7) << 4))) = v;
  }
  if (tid < JLEN / 4)
    *(f32x4*)&Dlds[tid * 4] = *(const f32x4*)(dst + jbase + tid * 4);
  __syncthreads();

  const size_t arow = (size_t)(rowg + r16) * N_ROWS;
  const float sv = src[rowg + r16];               // already * log2e
  const int cswz = (r16 & 7) << 4;

  f32x4 acc0 = {0,0,0,0}, acc1 = {0,0,0,0}, acc2 = {0,0,0,0}, acc3 = {0,0,0,0};
  float lp = 0.0f;

  i32x4 A[3][4];                     // 3-deep adj pipeline (static after unroll)

#pragma unroll 1
  for (int rep = 0; rep < REPEAT; ++rep) {   // DIAGNOSTIC passes, scaled below
    int z0 = 0;
    asm volatile("" : "+v"(z0));             // opaque 0: defeat cross-pass CSE
    const int cb0 = jbase + kq * 8 + z0;

    auto issueAdj = [&](int b, int i) {
      const int* p = adj + arow + cb0 + i * 64;    // plain cached loads
      A[b][0] = *(const i32x4*)(p);
      A[b][1] = *(const i32x4*)(p + 4);
      A[b][2] = *(const i32x4*)(p + 32);
      A[b][3] = *(const i32x4*)(p + 36);
    };

    issueAdj(0, 0); issueAdj(1, 1); issueAdj(2, 2);   // prologue: depth 3

#pragma unroll
    for (int i = 0; i < NI; ++i) {     // FULL unroll: A[i%3] indices static
#pragma unroll
      for (int h = 0; h < 2; ++h) {
        const int db = kq * 8 + i * 64 + h * 32;
        const f32x4 dA = *(const f32x4*)&Dlds[db];
        const f32x4 dB = *(const f32x4*)&Dlds[db + 4];
        const i32x4 aA = A[i % 3][2 * h];
        const i32x4 aB = A[i % 3][2 * h + 1];
        float p0, p1, p2, p3, p4, p5, p6, p7;
#define PE(pp, dd, aa) { float e = sv + (dd); e = fmaxf(e, LRELU_A * e); \
                         (pp) = ((aa) > 0) ? __builtin_amdgcn_exp2f(e) : 1.0f; }
        PE(p0, dA.x, aA.x) PE(p1, dA.y, aA.y) PE(p2, dA.z, aA.z) PE(p3, dA.w, aA.w)
        PE(p4, dB.x, aB.x) PE(p5, dB.y, aB.y) PE(p6, dB.z, aB.z) PE(p7, dB.w, aB.w)
#undef PE
        lp += ((p0 + p1) + (p2 + p3)) + ((p4 + p5) + (p6 + p7));
        union { s16x8 v; __hip_bfloat16 b[8]; } u;
        u.b[0] = __float2bfloat16(p0); u.b[1] = __float2bfloat16(p1);
        u.b[2] = __float2bfloat16(p2); u.b[3] = __float2bfloat16(p3);
        u.b[4] = __float2bfloat16(p4); u.b[5] = __float2bfloat16(p5);
        u.b[6] = __float2bfloat16(p6); u.b[7] = __float2bfloat16(p7);
        const char* bb = (const char*)Blds;
        const int colb = (i * 64 + h * 32 + kq * 8) * 2;
        const s16x8 b0 = *(const s16x8*)(bb + (0 * 16 + r16) * (JLEN * 2) + (colb ^ cswz));
        const s16x8 b1 = *(const s16x8*)(bb + (1 * 16 + r16) * (JLEN * 2) + (colb ^ cswz));
        const s16x8 b2 = *(const s16x8*)(bb + (2 * 16 + r16) * (JLEN * 2) + (colb ^ cswz));
        const s16x8 b3 = *(const s16x8*)(bb + (3 * 16 + r16) * (JLEN * 2) + (colb ^ cswz));
        acc0 = __builtin_amdgcn_mfma_f32_16x16x32_bf16(u.v, b0, acc0, 0, 0, 0);
        acc1 = __builtin_amdgcn_mfma_f32_16x16x32_bf16(u.v, b1, acc1, 0, 0, 0);
        acc2 = __builtin_amdgcn_mfma_f32_16x16x32_bf16(u.v, b2, acc2, 0, 0, 0);
        acc3 = __builtin_amdgcn_mfma_f32_16x16x32_bf16(u.v, b3, acc3, 0, 0, 0);
      }
      if (i + 3 < NI) issueAdj(i % 3, i + 3);   // refill just-freed buffer
    }
  }

  // ---- epilogue (scale by 1/REPEAT) ----
  const float sc = 1.0f / REPEAT;
  lp *= sc;
  lp += __shfl_xor(lp, 16, 64);       // lanes {l, l^16, l^32, l^48}: same row
  lp += __shfl_xor(lp, 32, 64);
  if (lane < 16) l_part[(size_t)s * N_ROWS + rowg + lane] = lp;

  // C/D layout: col(feat) = lane&15, row = (lane>>4)*4 + reg
#define STORE_ACC(av, nt) _Pragma("unroll") \
  for (int rg = 0; rg < 4; ++rg) { \
    const int row = rowg + kq * 4 + rg; \
    acc_part[((size_t)s * N_ROWS + row) * F_OUT + (nt) * 16 + r16] = (av)[rg] * sc; \
  }
  STORE_ACC(acc0, 0) STORE_ACC(acc1, 1) STORE_ACC(acc2, 2) STORE_ACC(acc3, 3)
#undef STORE_ACC
}

// ---------------- Kernel 3: combine partials, normalize, ELU ----------------
template<int S>
__global__ __launch_bounds__(256) void k3_combine(
    const float* __restrict__ acc_part, const float* __restrict__ l_part,
    float* __restrict__ out)
{
  const int idx = blockIdx.x * 256 + threadIdx.x;  // over N*F/4
  const int row = idx >> 4;          // F_OUT/4 = 16
  const int f4  = idx & 15;
  f32x4 h = {0.f, 0.f, 0.f, 0.f};
  float l = 0.f;
#pragma unroll
  for (int s = 0; s < S; ++s) {
    h += *(const f32x4*)(acc_part + ((size_t)s * N_ROWS + row) * F_OUT + 4 * f4);
    l += l_part[(size_t)s * N_ROWS + row];
  }
  const float inv = 1.0f / l;
  f32x4 o;
  {
    float v0 = h.x * inv; o.x = v0 > 0.f ? v0 : (__expf(v0) - 1.0f);
    float v1 = h.y * inv; o.y = v1 > 0.f ? v1 : (__expf(v1) - 1.0f);
    float v2 = h.z * inv; o.z = v2 > 0.f ? v2 : (__expf(v2) - 1.0f);
    float v3 = h.w * inv; o.w = v3 > 0.f ? v3 : (__expf(v3) - 1.0f);
  }
  *(f32x4*)(out + (size_t)row * F_OUT + 4 * f4) = o;
}

// ---------------- launch ----------------
extern "C" void kernel_launch(void* const* d_in, const int* in_sizes, int n_in,
                              void* d_out, int out_size, void* d_ws, size_t ws_size,
                              hipStream_t stream) {
  const float* x   = (const float*)d_in[0];
  const int*   adj = (const int*)d_in[1];
  const float* w   = (const float*)d_in[2];
  const float* a   = (const float*)d_in[3];
  float* out = (float*)d_out;
  char* ws = (char*)d_ws;

  short* whT      = (short*)(ws + OFF_WHT);
  float* src      = (float*)(ws + OFF_SRC);
  float* dst      = (float*)(ws + OFF_DST);
  float* l_part   = (float*)(ws + OFF_LP);
  float* acc_part = (float*)(ws + OFF_ACC);

  k1_proj<<<N_ROWS / 32, 256, 0, stream>>>(x, w, a, whT, src, dst);
  k2_attn<16><<<dim3(N_ROWS / 128, 16), 512, 0, stream>>>(adj, whT, src, dst,
                                                          acc_part, l_part);
  k3_combine<16><<<(N_ROWS * F_OUT / 4) / 256, 256, 0, stream>>>(acc_part, l_part, out);
}

// Round 15
// 99.739 us; speedup vs baseline: 1.9453x; 1.9453x over previous
//
#include <hip/hip_runtime.h>
#include <hip/hip_bf16.h>

// GraphAttentionLayer: out = elu( softmax_row( where(adj>0, lrelu(src_i+dst_j), 0) ) @ wh )
//
// R14 verdict: warm(L3) == cold pass (76us) -> NOT DRAM-delivery-bound; the
// scattered load cluster (16 rows x 32KB stride) aliases one L1-set/L2-index
// -> request serialization, pattern-invariant. Measured A/B matrix:
//   contiguous+cached 37us | scattered+cached 76 | contiguous+nt 74 | scat+nt 95.
// R15: R8's contiguous-adj architecture (2 rows x 512B per load instr, LDS-P
// redistribution, raw s_barrier + lgkmcnt(0) only so vmcnt prefetch survives
// the barrier) with PLAIN CACHED loads, S=8 (20KB LDS -> ~24 waves/CU).

constexpr int N_ROWS = 8192;
constexpr int F_IN   = 128;
constexpr int F_OUT  = 64;
#define LRELU_A 0.2f
#define LOG2E   1.4426950408889634f

// workspace layout (bytes)
constexpr size_t OFF_WHT  = 0;                    // 1 MiB bf16 [f][row]
constexpr size_t OFF_SRC  = 1048576;              // 8192 f32 (x log2e)
constexpr size_t OFF_DST  = OFF_SRC + 32768;      // 8192 f32 (x log2e)
constexpr size_t OFF_LP   = OFF_DST + 32768;      // S*8192 f32
constexpr size_t OFF_ACC  = OFF_LP + 16 * 32768;  // S*8192*64 f32

typedef __attribute__((ext_vector_type(4))) float f32x4;
typedef __attribute__((ext_vector_type(4))) int   i32x4;
typedef __attribute__((ext_vector_type(4))) short s16x4;
typedef __attribute__((ext_vector_type(8))) short s16x8;

static __device__ __forceinline__ short f2bf(float f) {
  unsigned u = __float_as_uint(f);
  u = (u + 0x7fffu + ((u >> 16) & 1u)) >> 16;  // RNE
  return (short)u;
}

// ---------------- Kernel 1: wh = x@w ; src/dst (x log2e) ; whT (bf16) -------
__global__ __launch_bounds__(256) void k1_proj(
    const float* __restrict__ x, const float* __restrict__ w,
    const float* __restrict__ a, short* __restrict__ whT,
    float* __restrict__ src, float* __restrict__ dst)
{
  const int lane = threadIdx.x & 63;   // = output feature f
  const int wid  = threadIdx.x >> 6;
  const int rowBase = blockIdx.x * 32 + wid * 8;   // 8 rows per wave

  float acc[8];
#pragma unroll
  for (int r = 0; r < 8; ++r) acc[r] = 0.0f;

#pragma unroll 1
  for (int kc = 0; kc < 4; ++kc) {     // K chunks of 32 — ONE wreg live
    float wreg[32];
#pragma unroll
    for (int kk = 0; kk < 32; ++kk)
      wreg[kk] = w[(kc * 32 + kk) * F_OUT + lane];   // coalesced
#pragma unroll
    for (int r = 0; r < 8; ++r) {
      const f32x4* xp = (const f32x4*)(x + (size_t)(rowBase + r) * F_IN + kc * 32);
#pragma unroll
      for (int q = 0; q < 8; ++q) {    // wave-uniform broadcast loads
        f32x4 xv = xp[q];
        acc[r] = fmaf(xv.x, wreg[4*q+0], acc[r]);
        acc[r] = fmaf(xv.y, wreg[4*q+1], acc[r]);
        acc[r] = fmaf(xv.z, wreg[4*q+2], acc[r]);
        acc[r] = fmaf(xv.w, wreg[4*q+3], acc[r]);
      }
    }
  }

  s16x8 hb;
#pragma unroll
  for (int r = 0; r < 8; ++r) hb[r] = f2bf(acc[r]);
  *(s16x8*)&whT[(size_t)lane * N_ROWS + rowBase] = hb;

  const float aS = a[lane];
  const float aD = a[F_OUT + lane];
#pragma unroll
  for (int r = 0; r < 8; ++r) {
    float ts = acc[r] * aS;
    float td = acc[r] * aD;
#pragma unroll
    for (int off = 32; off > 0; off >>= 1) {
      ts += __shfl_xor(ts, off, 64);
      td += __shfl_xor(td, off, 64);
    }
    if (lane == 0) {
      src[rowBase + r] = ts * LOG2E;   // log2-domain scores
      dst[rowBase + r] = td * LOG2E;
    }
  }
}

// ---------------- Kernel 2: contiguous-adj, LDS-P, raw-barrier pipeline -----
// grid: (N/32, S) x 256 threads (4 waves). BR=32 rows/block, BC=128 cols/tile.
// Phase-A: contiguous CACHED adj loads -> P -> swizzled LDS (dbuf). Phase-B:
// MFMA, A from LDS P, B-frags from L2-hot whT (issued oldest-per-tile).
// One raw s_barrier + lgkmcnt(0) per tile; vmcnt prefetch crosses it.
template<int S>
__global__ __launch_bounds__(256, 3) void k2_attn(
    const int* __restrict__ adj, const short* __restrict__ whT,
    const float* __restrict__ src, const float* __restrict__ dst,
    float* __restrict__ acc_part, float* __restrict__ l_part)
{
  constexpr int JLEN = N_ROWS / S;   // 1024 at S=8
  constexpr int BC   = 128;
  constexpr int BR   = 32;
  constexpr int NT   = JLEN / BC;    // 8 (even)
  __shared__ short Plds[2][BR * BC]; // 2 x 8KB, byte ^= (row&7)<<4 swizzle
  __shared__ float Dlds[JLEN];       // 4KB

  const int tid  = threadIdx.x;
  const int lane = tid & 63;
  const int wid  = tid >> 6;
  const int s    = blockIdx.y;
  const int jbase = s * JLEN;
  const int rowg = blockIdx.x * BR;
  const int r16  = lane & 15;
  const int kq   = lane >> 4;
  const int l32  = lane & 31;
  const int lh   = lane >> 5;
  const int mt   = wid & 1;
  const int ntb  = (wid >> 1) * 2;

  // stage dst slice; single __syncthreads (pipeline hasn't started)
  for (int t4 = tid * 4; t4 < JLEN; t4 += 1024)
    *(f32x4*)&Dlds[t4] = *(const f32x4*)(dst + jbase + t4);
  __syncthreads();

  float srcv[8];
#pragma unroll
  for (int r = 0; r < 8; ++r) srcv[r] = src[rowg + wid * 8 + r];

  // contiguous adj base: lane covers 16B of row (wid*8 + rr*2 + lh)
  const size_t adjb = (size_t)(rowg + wid * 8 + lh) * N_ROWS + jbase + l32 * 4;

  f32x4 acc0 = {0,0,0,0}, acc1 = {0,0,0,0};
  float lp[4] = {0.f, 0.f, 0.f, 0.f};
  i32x4 Aa[4], Ab[4];
  s16x8 Bc[8];

  auto issueAdj = [&](i32x4* A, int i) {
#pragma unroll
    for (int rr = 0; rr < 4; ++rr)    // 2 rows x 512B contiguous per instr
      A[rr] = *(const i32x4*)(adj + adjb + (size_t)rr * 2 * N_ROWS + i * BC);
  };

  auto body = [&](i32x4* CUR, i32x4* NXT, int i) {
    const int j0 = jbase + i * BC;
    // --- [1] B(i) frags (L2-hot whT) — OLDEST vmem of this tile ---
    {
      const short* bq = whT + j0 + kq * 8;
#pragma unroll
      for (int nt = 0; nt < 2; ++nt)
#pragma unroll
        for (int kw = 0; kw < 4; ++kw)
          Bc[nt * 4 + kw] = *(const s16x8*)(bq
              + (size_t)((ntb + nt) * 16 + r16) * N_ROWS + kw * 32);
    }
    __builtin_amdgcn_sched_barrier(0);
    // --- [2] adj(i+1) prefetch — newest; survives all waits below ---
    if (i + 1 < NT) issueAdj(NXT, i + 1);
    __builtin_amdgcn_sched_barrier(0);
    // --- [3] phase A: P(i) from CUR (vmcnt wait leaves B+adj in flight) ---
    {
      short* pb = &Plds[i & 1][0];
      const f32x4 d4 = *(const f32x4*)&Dlds[i * BC + l32 * 4];
#pragma unroll
      for (int rr = 0; rr < 4; ++rr) {
        const i32x4 av = CUR[rr];
        const float sv = lh ? srcv[rr * 2 + 1] : srcv[rr * 2];
        float p0, p1, p2, p3;
#define PE(pp, dd, aa) { float e = sv + (dd); e = fmaxf(e, LRELU_A * e); \
                         (pp) = ((aa) > 0) ? __builtin_amdgcn_exp2f(e) : 1.0f; }
        PE(p0, d4.x, av.x) PE(p1, d4.y, av.y) PE(p2, d4.z, av.z) PE(p3, d4.w, av.w)
#undef PE
        lp[rr] += (p0 + p1) + (p2 + p3);
        union { s16x4 v; __hip_bfloat16 b[4]; } u;
        u.b[0] = __float2bfloat16(p0); u.b[1] = __float2bfloat16(p1);
        u.b[2] = __float2bfloat16(p2); u.b[3] = __float2bfloat16(p3);
        const int rowL = wid * 8 + rr * 2 + lh;
        *(s16x4*)((char*)pb + rowL * 256 + ((l32 * 8) ^ ((rowL & 7) << 4))) = u.v;
      }
    }
    // --- [4] LDS visibility + RAW barrier (no vmcnt drain!) ---
    asm volatile("s_waitcnt lgkmcnt(0)" ::: "memory");
    __builtin_amdgcn_sched_barrier(0);
    __builtin_amdgcn_s_barrier();
    // --- [5] MFMA: A from swizzled LDS, B from regs ---
    {
      const char* ab = (const char*)&Plds[i & 1][0] + (mt * 16 + r16) * 256;
      const int aswz = (r16 & 7) << 4;
#pragma unroll
      for (int kw = 0; kw < 4; ++kw) {
        const s16x8 afr = *(const s16x8*)(ab + ((kw * 64 + kq * 16) ^ aswz));
        acc0 = __builtin_amdgcn_mfma_f32_16x16x32_bf16(afr, Bc[kw],     acc0, 0, 0, 0);
        acc1 = __builtin_amdgcn_mfma_f32_16x16x32_bf16(afr, Bc[4 + kw], acc1, 0, 0, 0);
      }
    }
    // no second barrier: next phase-A writes buffer (i+1)&1, whose readers
    // (MFMA(i-1)) completed their ds_reads before passing barrier(i).
  };

  issueAdj(Aa, 0);
#pragma unroll 1
  for (int i = 0; i < NT; i += 2) {        // static buffer names
    body(Aa, Ab, i);
    body(Ab, Aa, i + 1);
  }

  // ---- epilogue ----
#pragma unroll
  for (int rr = 0; rr < 4; ++rr) {
    float v = lp[rr];
#pragma unroll
    for (int off = 1; off < 32; off <<= 1) v += __shfl_xor(v, off, 64);
    if (l32 == 0)
      l_part[(size_t)s * N_ROWS + rowg + wid * 8 + rr * 2 + lh] = v;
  }
  // C/D layout: col(feat) = lane&15, row = (lane>>4)*4 + reg
#pragma unroll
  for (int rg = 0; rg < 4; ++rg) {
    const int row = rowg + mt * 16 + kq * 4 + rg;
    acc_part[((size_t)s * N_ROWS + row) * F_OUT + ntb * 16 + r16]       = acc0[rg];
    acc_part[((size_t)s * N_ROWS + row) * F_OUT + (ntb + 1) * 16 + r16] = acc1[rg];
  }
}

// ---------------- Kernel 3: combine partials, normalize, ELU ----------------
template<int S>
__global__ __launch_bounds__(256) void k3_combine(
    const float* __restrict__ acc_part, const float* __restrict__ l_part,
    float* __restrict__ out)
{
  const int idx = blockIdx.x * 256 + threadIdx.x;  // over N*F/4
  const int row = idx >> 4;          // F_OUT/4 = 16
  const int f4  = idx & 15;
  f32x4 h = {0.f, 0.f, 0.f, 0.f};
  float l = 0.f;
#pragma unroll
  for (int s = 0; s < S; ++s) {
    h += *(const f32x4*)(acc_part + ((size_t)s * N_ROWS + row) * F_OUT + 4 * f4);
    l += l_part[(size_t)s * N_ROWS + row];
  }
  const float inv = 1.0f / l;
  f32x4 o;
  {
    float v0 = h.x * inv; o.x = v0 > 0.f ? v0 : (__expf(v0) - 1.0f);
    float v1 = h.y * inv; o.y = v1 > 0.f ? v1 : (__expf(v1) - 1.0f);
    float v2 = h.z * inv; o.z = v2 > 0.f ? v2 : (__expf(v2) - 1.0f);
    float v3 = h.w * inv; o.w = v3 > 0.f ? v3 : (__expf(v3) - 1.0f);
  }
  *(f32x4*)(out + (size_t)row * F_OUT + 4 * f4) = o;
}

// ---------------- launch ----------------
extern "C" void kernel_launch(void* const* d_in, const int* in_sizes, int n_in,
                              void* d_out, int out_size, void* d_ws, size_t ws_size,
                              hipStream_t stream) {
  const float* x   = (const float*)d_in[0];
  const int*   adj = (const int*)d_in[1];
  const float* w   = (const float*)d_in[2];
  const float* a   = (const float*)d_in[3];
  float* out = (float*)d_out;
  char* ws = (char*)d_ws;

  short* whT      = (short*)(ws + OFF_WHT);
  float* src      = (float*)(ws + OFF_SRC);
  float* dst      = (float*)(ws + OFF_DST);
  float* l_part   = (float*)(ws + OFF_LP);
  float* acc_part = (float*)(ws + OFF_ACC);

  k1_proj<<<N_ROWS / 32, 256, 0, stream>>>(x, w, a, whT, src, dst);
  k2_attn<8><<<dim3(N_ROWS / 32, 8), 256, 0, stream>>>(adj, whT, src, dst,
                                                       acc_part, l_part);
  k3_combine<8><<<(N_ROWS * F_OUT / 4) / 256, 256, 0, stream>>>(acc_part, l_part, out);
}